// Round 9
// baseline (106.664 us; speedup 1.0000x reference)
//
#include <hip/hip_runtime.h>
#include <math.h>

// Problem sizes (fixed by reference setup_inputs)
#define BATCH 8
#define NPTS  8192   // pred/full points per batch
#define PPTS  2048   // partial points per batch
#define DLAT  512    // latent dim

// R8 post-mortem: v_min3_i32 with AGPR sources does NOT assemble on gfx950 —
// VALU can't read AGPRs (only MFMA operands can). So AGPR-resident
// accumulators ALWAYS cost v_accvgpr_read per element. Serial-issue model
// closes: wall ~= (32 cyc/MFMA + 2 cyc/VALU-inst) per SIMD; the ~64 moves +
// 16-op min trees per j-iter are the fat. R9 = the untested combination:
//   asm MFMA "=&v" (arch-VGPR results -> moves impossible)
// x asm v_min3_i32 all-"v"   (8 min ops/tile guaranteed)
// Bit-identical numerics to R7 (absmax 0.0): same MFMA, same int-min order,
// same clamp — only register placement changes.
#define YSPLIT 16
#define CHUNK  (NPTS / YSPLIT)   // 512 y points per block, staged once (16 KB)
#define XBLK   512               // x points per block (4 waves x 4 col-groups)

typedef __attribute__((ext_vector_type(8)))  short short8;    // 8 bf16 (4 VGPR)
typedef __attribute__((ext_vector_type(16))) float floatx16;  // MFMA 32x32 C/D

// Workspace (float elements):
//   [0..4)    acc: sum_pf, sum_fp, sum_fid, sum_kl   (zeroed by minpass blk 0)
//   [4]       uint completion counter                 (zeroed by minpass blk 0)
//   [8..)     YSPLIT segments of min-d^2 (pf | fp | fid), plain block-owned
//             stores (every slot written unconditionally -> no init pass).
#define SEG      (2 * BATCH * NPTS + BATCH * PPTS)   // 147456 floats (~0.6 MB)
#define DIR_PF   0
#define DIR_FP   (BATCH * NPTS)
#define DIR_FID  (2 * BATCH * NPTS)
#define OFF_SEG  8

__device__ __forceinline__ unsigned short f2bf(float f) {  // RNE float->bf16
    unsigned int u = __float_as_uint(f);
    return (unsigned short)((u + 0x7FFFu + ((u >> 16) & 1u)) >> 16);
}
__device__ __forceinline__ float bf2f(unsigned short s) {
    return __uint_as_float(((unsigned int)s) << 16);
}

__device__ __forceinline__ int imin2(int a, int b) { return a < b ? a : b; }

// MFMA with arch-VGPR result tuple: "=&v" early-clobber guarantees the
// 16 result regs are VGPRs, so the min tree consumes them directly —
// v_accvgpr_read is impossible by construction.
__device__ __forceinline__ floatx16 mfma_v(short8 a, short8 b, floatx16 c) {
    floatx16 d;
    asm("v_mfma_f32_32x32x16_bf16 %0, %1, %2, %3"
        : "=&v"(d) : "v"(a), "v"(b), "v"(c));
    return d;
}

// Guaranteed single-instruction 3-input signed-int min, VGPR sources only
// (AGPR sources rejected by the assembler — R8).
__device__ __forceinline__ int min3i(int a, int b, int c) {
    int r;
    asm("v_min3_i32 %0, %1, %2, %3" : "=v"(r) : "v"(a), "v"(b), "v"(c));
    return r;
}

// min over 16 VGPR-resident accumulator regs + carry-in, int domain.
// Exactly 8 v_min3_i32, zero moves. Valid: T >= -eps so signed-int order
// == float order (tie band absorbed by the final clamp; R7 absmax 0.0).
__device__ __forceinline__ int min16i(floatx16 d, int prev) {
    const int l0 = min3i(__float_as_int(d[0]),  __float_as_int(d[1]),  __float_as_int(d[2]));
    const int l1 = min3i(__float_as_int(d[3]),  __float_as_int(d[4]),  __float_as_int(d[5]));
    const int l2 = min3i(__float_as_int(d[6]),  __float_as_int(d[7]),  __float_as_int(d[8]));
    const int l3 = min3i(__float_as_int(d[9]),  __float_as_int(d[10]), __float_as_int(d[11]));
    const int l4 = min3i(__float_as_int(d[12]), __float_as_int(d[13]), __float_as_int(d[14]));
    const int m0 = min3i(l0, l1, l2);
    const int m1 = min3i(l3, l4, __float_as_int(d[15]));
    return min3i(m0, m1, prev);
}

// Encode one y point + its norm into two uint4 k-half records.
// A(y): k0-2 yh | k3-5 yl | k6-8 yh | k9 yn_h | k10 yn_l | k11 1 | k12 1
__device__ __forceinline__ void encodeY(float y0, float y1, float y2,
                                        uint4* r0, uint4* r1) {
    const unsigned short h0 = f2bf(y0), h1 = f2bf(y1), h2 = f2bf(y2);
    const unsigned short l0 = f2bf(y0 - bf2f(h0));
    const unsigned short l1 = f2bf(y1 - bf2f(h1));
    const unsigned short l2 = f2bf(y2 - bf2f(h2));
    const float yn = fmaf(y0, y0, fmaf(y1, y1, y2 * y2));
    const unsigned short nh = f2bf(yn);
    const unsigned short nl = f2bf(yn - bf2f(nh));
    const unsigned int one = 0x3F80u;
    r0->x = (unsigned int)h0 | ((unsigned int)h1 << 16);  // k0,k1: yh.x,yh.y
    r0->y = (unsigned int)h2 | ((unsigned int)l0 << 16);  // k2,k3: yh.z,yl.x
    r0->z = (unsigned int)l1 | ((unsigned int)l2 << 16);  // k4,k5: yl.y,yl.z
    r0->w = (unsigned int)h0 | ((unsigned int)h1 << 16);  // k6,k7: yh.x,yh.y
    r1->x = (unsigned int)h2 | ((unsigned int)nh << 16);  // k8,k9: yh.z,yn_h
    r1->y = (unsigned int)nl | (one << 16);               // k10: yn_l, k11: 1
    r1->z = one;                                          // k12: 1, k13: 0
    r1->w = 0u;                                           // k14,k15: 0
}

// ---------------------------------------------------------------- min pass
// K-slot scheme (13 of 16 used):
//   A(y): k0-2 yh | k3-5 yl | k6-8 yh | k9-10 yn_h,yn_l | k11-12 1,1
//   B(x): k0-2 -2xh | k3-5 -2xh | k6-8 -2xl | k9-10 1,1 | k11-12 xn_h,xn_l
//   => T = |y|^2 - 2 x.y + |x|^2 ~ |x-y|^2 >= -eps (split residual ~5e-4).
// Block = 256 thr = 4 waves; block owns 512 x; wave owns 128 x (4 col-groups).
// Grid = 8 batches * 36 x-subblocks * YSPLIT = 4608 blocks (18/CU).
__global__ __launch_bounds__(256, 4) void minpass_kernel(
        const float* __restrict__ pred,
        const float* __restrict__ full,
        const float* __restrict__ partial,
        float* __restrict__ wsf) {
    const int bid = blockIdx.x;          // 8 batches * 36 subs * YSPLIT
    const int ys  = bid % YSPLIT;
    const int r   = bid / YSPLIT;
    const int b   = r / 36;
    const int s   = r % 36;

    const int t = threadIdx.x;

    // block 0 zeroes acc + counter for the reduce kernel (stream ordering)
    if (bid == 0) {
        if (t < 4) wsf[t] = 0.0f;
        if (t == 4) ((unsigned int*)wsf)[4] = 0u;
    }

    const float* xset; const float* yset; int minoff; int xbase;
    if (s < 16)      { xset = pred;    yset = full; xbase = b*NPTS + s*XBLK;
                       minoff = OFF_SEG + ys*SEG + DIR_PF  + b*NPTS + s*XBLK; }
    else if (s < 32) { xset = full;    yset = pred; xbase = b*NPTS + (s-16)*XBLK;
                       minoff = OFF_SEG + ys*SEG + DIR_FP  + b*NPTS + (s-16)*XBLK; }
    else             { xset = partial; yset = pred; xbase = b*PPTS + (s-32)*XBLK;
                       minoff = OFF_SEG + ys*SEG + DIR_FID + b*PPTS + (s-32)*XBLK; }

    const int lane = t & 63;
    const int wid  = t >> 6;
    const int l31  = lane & 31;
    const int half = lane >> 5;

    __shared__ uint4 sY[2][CHUNK];   // y records [k-half][point]  (16 KB)

    // ---- per-lane x encode: lane needs x points xw + {0,32,64,96} + l31,
    // and only the k-half record matching its lane half. Encode in registers.
    const int xw = wid * 128;
    short8 bf0, bf1, bf2, bf3;
#pragma unroll
    for (int k = 0; k < 4; ++k) {
        const float* xp = xset + (size_t)(xbase + xw + k * 32 + l31) * 3;
        const float x0 = xp[0], x1 = xp[1], x2 = xp[2];
        const float m0 = -2.0f*x0, m1 = -2.0f*x1, m2 = -2.0f*x2;
        const unsigned short h0 = f2bf(m0), h1 = f2bf(m1), h2 = f2bf(m2);
        const unsigned short l0 = f2bf(m0 - bf2f(h0));
        const unsigned short l1 = f2bf(m1 - bf2f(h1));
        const unsigned short l2 = f2bf(m2 - bf2f(h2));
        const float xn = fmaf(x0, x0, fmaf(x1, x1, x2 * x2));
        const unsigned short nh = f2bf(xn);
        const unsigned short nl = f2bf(xn - bf2f(nh));
        const unsigned int one = 0x3F80u;
        uint4 r0, r1;
        r0.x = (unsigned int)h0 | ((unsigned int)h1 << 16);  // k0,k1: -2xh.x,-2xh.y
        r0.y = (unsigned int)h2 | ((unsigned int)h0 << 16);  // k2,k3: -2xh.z,-2xh.x
        r0.z = (unsigned int)h1 | ((unsigned int)h2 << 16);  // k4,k5: -2xh.y,-2xh.z
        r0.w = (unsigned int)l0 | ((unsigned int)l1 << 16);  // k6,k7: -2xl.x,-2xl.y
        r1.x = (unsigned int)l2 | (one << 16);               // k8,k9: -2xl.z,1
        r1.y = one | ((unsigned int)nh << 16);               // k10: 1, k11: xn_h
        r1.z = (unsigned int)nl;                             // k12: xn_l, k13: 0
        r1.w = 0u;                                           // k14,k15: 0
        const uint4 rec = half ? r1 : r0;
        const short8 bfv = *(const short8*)&rec;
        if (k == 0) bf0 = bfv;
        else if (k == 1) bf1 = bfv;
        else if (k == 2) bf2 = bfv;
        else bf3 = bfv;
    }

    // ---- stage the block's ENTIRE y range once (2 points per thread)
    const float* ypts = yset + (size_t)(b * NPTS + ys * CHUNK) * 3;
#pragma unroll
    for (int i = t; i < CHUNK; i += 256) {
        const float* yp = ypts + (size_t)i * 3;
        uint4 r0, r1;
        encodeY(yp[0], yp[1], yp[2], &r0, &r1);
        sY[0][i] = r0; sY[1][i] = r1;
    }
    __syncthreads();   // the ONLY barrier

    const floatx16 zc = {0,0,0,0, 0,0,0,0, 0,0,0,0, 0,0,0,0};
    int cmin0 = 0x7FFFFFFF, cmin1 = 0x7FFFFFFF,
        cmin2 = 0x7FFFFFFF, cmin3 = 0x7FFFFFFF;

    const uint4* sYh = &sY[half][0];

#define JBODY()                                              \
    do {                                                     \
        const floatx16 d0 = mfma_v(af, bf0, zc);             \
        const floatx16 d1 = mfma_v(af, bf1, zc);             \
        cmin0 = min16i(d0, cmin0);                           \
        const floatx16 d2 = mfma_v(af, bf2, zc);             \
        cmin1 = min16i(d1, cmin1);                           \
        const floatx16 d3 = mfma_v(af, bf3, zc);             \
        cmin2 = min16i(d2, cmin2);                           \
        cmin3 = min16i(d3, cmin3);                           \
    } while (0)

    short8 af = *(const short8*)&sYh[l31];
#pragma unroll
    for (int j = 0; j < CHUNK / 32 - 1; ++j) {
        const short8 afn = *(const short8*)&sYh[(j + 1) * 32 + l31];  // prefetch
        JBODY();
        af = afn;
    }
    JBODY();   // peeled last iteration (no prefetch)
#undef JBODY

    // merge the two lane-halves (same column, different row halves);
    // clamp the tiny-negative band to 0 and store as float (plain store —
    // this block owns its segment slice).
    const int m0 = imin2(cmin0, __shfl_xor(cmin0, 32, 64));
    const int m1 = imin2(cmin1, __shfl_xor(cmin1, 32, 64));
    const int m2 = imin2(cmin2, __shfl_xor(cmin2, 32, 64));
    const int m3 = imin2(cmin3, __shfl_xor(cmin3, 32, 64));
    if (lane < 32) {
        wsf[minoff + xw + l31]      = fmaxf(__int_as_float(m0), 0.0f);
        wsf[minoff + xw + 32 + l31] = fmaxf(__int_as_float(m1), 0.0f);
        wsf[minoff + xw + 64 + l31] = fmaxf(__int_as_float(m2), 0.0f);
        wsf[minoff + xw + 96 + l31] = fmaxf(__int_as_float(m3), 0.0f);
    }
}

// ---------------------------------------------------------------- reductions
__device__ __forceinline__ float waveReduceSum(float v) {
#pragma unroll
    for (int o = 32; o > 0; o >>= 1) v += __shfl_down(v, o, 64);
    return v;
}

__device__ __forceinline__ float blockReduceSum(float v) {
    __shared__ float wsum[4];
    const int lane = threadIdx.x & 63;
    const int wid  = threadIdx.x >> 6;
    v = waveReduceSum(v);
    if (lane == 0) wsum[wid] = v;
    __syncthreads();
    if (wid == 0) {
        v = (lane < ((int)blockDim.x >> 6)) ? wsum[lane] : 0.0f;
        v = waveReduceSum(v);
    }
    return v;
}

// Blocks 0..63: pf (1024 slots each), 64..127: fp, 128..143: fid, 144: kl.
// Same slot->thread->order mapping as the absmax-0.0 rounds; the 16-way
// segment min is deterministic and exact (min), so summation order is
// unchanged.
#define NRED_BLOCKS 145
__global__ __launch_bounds__(256) void reduce_finalize_kernel(
        float* __restrict__ wsf,
        const float* __restrict__ mu,
        const float* __restrict__ logvar,
        float* __restrict__ out) {
    float* acc = wsf;
    unsigned int* cnt = (unsigned int*)wsf + 4;
    const int bid = blockIdx.x;
    const int t   = threadIdx.x;

    float v = 0.0f;
    int accIdx;
    if (bid < 144) {
        int base;
        if (bid < 64)       { accIdx = 0; base = DIR_PF  + bid * 1024;         }
        else if (bid < 128) { accIdx = 1; base = DIR_FP  + (bid - 64) * 1024;  }
        else                { accIdx = 2; base = DIR_FID + (bid - 128) * 1024; }
#pragma unroll
        for (int k = 0; k < 4; ++k) {
            const int i = OFF_SEG + base + k * 256 + t;
            float m = wsf[i];
#pragma unroll
            for (int sg = 1; sg < YSPLIT; ++sg) m = fminf(m, wsf[i + sg * SEG]);
            v += sqrtf(fmaxf(m, 1e-12f));
        }
    } else {
        accIdx = 3;
#pragma unroll
        for (int k = 0; k < BATCH * DLAT / 256; ++k) {
            const int i = k * 256 + t;
            const float m = mu[i];
            const float l = logvar[i];
            v += -0.5f * (1.0f + l - m * m - expf(l));
        }
    }

    v = blockReduceSum(v);
    if (t == 0) {
        atomicAdd(&acc[accIdx], v);
        __threadfence();
        const unsigned int done = atomicAdd(cnt, 1u);
        if (done == NRED_BLOCKS - 1) {
            const float s_pf  = atomicAdd(&acc[0], 0.0f);
            const float s_fp  = atomicAdd(&acc[1], 0.0f);
            const float s_fid = atomicAdd(&acc[2], 0.0f);
            const float s_kl  = atomicAdd(&acc[3], 0.0f);
            const float cd  = 0.5f * (s_pf / (float)(BATCH * NPTS) +
                                      s_fp / (float)(BATCH * NPTS));
            const float fid = s_fid / (float)(BATCH * PPTS);
            const float kl  = s_kl / (float)BATCH;
            out[0] = cd + 0.01f * kl + 0.5f * fid;  // CD_W=1, BETA=0.01, FID_W=0.5
            out[1] = cd;
            out[2] = kl;
            out[3] = fid;
        }
    }
}

// ---------------------------------------------------------------- launch
extern "C" void kernel_launch(void* const* d_in, const int* in_sizes, int n_in,
                              void* d_out, int out_size, void* d_ws, size_t ws_size,
                              hipStream_t stream) {
    const float* pred    = (const float*)d_in[0];
    const float* full    = (const float*)d_in[1];
    const float* partial = (const float*)d_in[2];
    const float* mu      = (const float*)d_in[3];
    const float* logvar  = (const float*)d_in[4];
    float* out = (float*)d_out;
    float* wsf = (float*)d_ws;

    // ws need: (8 + 16*147456)*4 ~ 9.4 MB (workspace is ~268 MB).
    // No init pass needed: every segment slot is written unconditionally.

    // 1. MFMA min-distance pass (block 0 also zeroes acc+counter)
    minpass_kernel<<<8 * 36 * YSPLIT, 256, 0, stream>>>(pred, full, partial, wsf);

    // 2. all reductions + finalize in one dispatch
    reduce_finalize_kernel<<<NRED_BLOCKS, 256, 0, stream>>>(wsf, mu, logvar, out);
}

// Round 10
// 103.940 us; speedup vs baseline: 1.0262x; 1.0262x over previous
//
#include <hip/hip_runtime.h>
#include <math.h>

// Problem sizes (fixed by reference setup_inputs)
#define BATCH 8
#define NPTS  8192   // pred/full points per batch
#define PPTS  2048   // partial points per batch
#define DLAT  512    // latent dim

// FINAL (R10): revert to the best measured configuration (R2: 103.2 us,
// absmax 0.0). Session ledger (minpass wall across structural variants):
//   R0 40.8 | R2 41.2 | R4 42.7 | R5 41.4 | R6 43.7 | R7 43.1 | R9 45.2
// Levers tried and NULL: mid-loop barriers removed (R2), occupancy 24->57%
// (R4), min-op count halved (R1/R7/R9), MFMA register placement via asm
// (R5/R6/R9), software-pipeline rotation (R6), int-domain min (R7/R9).
// Hard facts learned:
//  - VALU cannot read AGPRs on gfx950 (R8 assembler rejection).
//  - Inline asm touching MFMA results races (compiler's MFMA hazard
//    recognizer doesn't cover asm): every asm round absmax>0 (R1/R5/R6/R9),
//    every asm-free round absmax==0. Asm is unsafe here without verifiable
//    s_nop padding (needs disasm access).
//  - Wall decomposition: matrix pipe 15.4 us (at its throughput floor),
//    pure-VALU ~10-11 us (min tree + staging, near its floor), rest =
//    per-wave MFMA-latency stalls; occupancy capped ~5 blocks/CU by the
//    UNIFIED VGPR+AGPR budget (~100/wave), and forcing more spills (R3).
#define YSPLIT 8
#define CHUNK  (NPTS / YSPLIT)   // 1024 y points per block, staged once (32 KB)
#define XBLK   512               // x points per block (4 waves x 4 col-groups)

typedef __attribute__((ext_vector_type(8)))  short short8;    // 8 bf16 (4 VGPR)
typedef __attribute__((ext_vector_type(16))) float floatx16;  // MFMA 32x32 C/D

// Workspace (float elements):
//   [0..4)    acc: sum_pf, sum_fp, sum_fid, sum_kl   (zeroed by minpass blk 0)
//   [4]       uint completion counter                 (zeroed by minpass blk 0)
//   [8..)     ONE segment of min-d^2 (pf | fp | fid), initialized to ~3.4e38
//             by hipMemsetAsync(0x7F), combined via atomicMin (uint order ==
//             float order for non-negative floats).
#define SEG      (2 * BATCH * NPTS + BATCH * PPTS)   // 147456 floats (~0.6 MB)
#define DIR_PF   0
#define DIR_FP   (BATCH * NPTS)
#define DIR_FID  (2 * BATCH * NPTS)
#define OFF_SEG  8

__device__ __forceinline__ unsigned short f2bf(float f) {  // RNE float->bf16
    unsigned int u = __float_as_uint(f);
    return (unsigned short)((u + 0x7FFFu + ((u >> 16) & 1u)) >> 16);
}
__device__ __forceinline__ float bf2f(unsigned short s) {
    return __uint_as_float(((unsigned int)s) << 16);
}

// min over 16 accumulator regs (16 rows of this lane's column) + carry-in.
// Plain fminf tree — exact, and the compiler handles the MFMA-result
// read hazards for builtin MFMA consumers (asm variants raced; see header).
__device__ __forceinline__ float min16(floatx16 d, float prev) {
    float a0 = fminf(fminf(d[0],  d[1]),  d[2]);
    float a1 = fminf(fminf(d[3],  d[4]),  d[5]);
    float a2 = fminf(fminf(d[6],  d[7]),  d[8]);
    float a3 = fminf(fminf(d[9],  d[10]), d[11]);
    float a4 = fminf(fminf(d[12], d[13]), d[14]);
    float b0 = fminf(fminf(a0, a1), a2);
    float b1 = fminf(fminf(a3, a4), d[15]);
    return fminf(fminf(b0, b1), prev);
}

// Encode one y point + its norm into two uint4 k-half records.
__device__ __forceinline__ void encodeY(float y0, float y1, float y2,
                                        uint4* r0, uint4* r1) {
    const unsigned short h0 = f2bf(y0), h1 = f2bf(y1), h2 = f2bf(y2);
    const unsigned short l0 = f2bf(y0 - bf2f(h0));
    const unsigned short l1 = f2bf(y1 - bf2f(h1));
    const unsigned short l2 = f2bf(y2 - bf2f(h2));
    const float yn = fmaf(y0, y0, fmaf(y1, y1, y2 * y2));
    const unsigned short nh = f2bf(yn);
    const unsigned short nl = f2bf(yn - bf2f(nh));
    r0->x = (unsigned int)h0 | ((unsigned int)h1 << 16);  // k0,k1: yh.x,yh.y
    r0->y = (unsigned int)h2 | ((unsigned int)l0 << 16);  // k2,k3: yh.z,yl.x
    r0->z = (unsigned int)l1 | ((unsigned int)l2 << 16);  // k4,k5: yl.y,yl.z
    r0->w = (unsigned int)h0 | ((unsigned int)h1 << 16);  // k6,k7: yh.x,yh.y
    r1->x = (unsigned int)h2 | ((unsigned int)nh << 16);  // k8,k9: yh.z,yn_h
    r1->y = (unsigned int)nl;                             // k10, k11=0
    r1->z = 0u; r1->w = 0u;
}

// ---------------------------------------------------------------- min pass
// K-slot scheme (11 of 16 used):
//   A(y): k0-2 yh | k3-5 yl | k6-8 yh | k9 yn_h | k10 yn_l | rest 0
//   B(x): k0-2 -2xh | k3-5 -2xh | k6-8 -2xl | k9 1 | k10 1 | rest 0
//   => T = |y|^2 - 2 x.y (split residual ~1e-4); |x|^2 added post-min in fp32.
// Block = 256 thr = 4 waves; block owns 512 x; wave owns 128 x (4 col-groups).
// Grid = 8 batches * 36 x-subblocks * YSPLIT = 2304 blocks.
__global__ __launch_bounds__(256, 4) void minpass_kernel(
        const float* __restrict__ pred,
        const float* __restrict__ full,
        const float* __restrict__ partial,
        float* __restrict__ wsf) {
    const int bid = blockIdx.x;          // 8 batches * 36 subs * YSPLIT
    const int ys  = bid % YSPLIT;
    const int r   = bid / YSPLIT;
    const int b   = r / 36;
    const int s   = r % 36;

    const int t = threadIdx.x;

    // block 0 zeroes acc + counter for the reduce kernel (stream ordering)
    if (bid == 0) {
        if (t < 4) wsf[t] = 0.0f;
        if (t == 4) ((unsigned int*)wsf)[4] = 0u;
    }

    const float* xset; const float* yset; int minoff; int xbase;
    if (s < 16)      { xset = pred;    yset = full; xbase = b*NPTS + s*XBLK;
                       minoff = OFF_SEG + DIR_PF  + b*NPTS + s*XBLK; }
    else if (s < 32) { xset = full;    yset = pred; xbase = b*NPTS + (s-16)*XBLK;
                       minoff = OFF_SEG + DIR_FP  + b*NPTS + (s-16)*XBLK; }
    else             { xset = partial; yset = pred; xbase = b*PPTS + (s-32)*XBLK;
                       minoff = OFF_SEG + DIR_FID + b*PPTS + (s-32)*XBLK; }

    const int lane = t & 63;
    const int wid  = t >> 6;
    const int l31  = lane & 31;
    const int half = lane >> 5;

    __shared__ uint4 sY[2][CHUNK];   // y records [k-half][point]  (32 KB)

    // ---- per-lane x encode: lane needs x points xw + {0,32,64,96} + l31,
    // and only the k-half record matching its lane half. Encode in registers.
    const int xw = wid * 128;
    short8 bf0, bf1, bf2, bf3;
    float  xn0, xn1, xn2, xn3;
#pragma unroll
    for (int k = 0; k < 4; ++k) {
        const float* xp = xset + (size_t)(xbase + xw + k * 32 + l31) * 3;
        const float x0 = xp[0], x1 = xp[1], x2 = xp[2];
        const float m0 = -2.0f*x0, m1 = -2.0f*x1, m2 = -2.0f*x2;
        const unsigned short h0 = f2bf(m0), h1 = f2bf(m1), h2 = f2bf(m2);
        const unsigned short l0 = f2bf(m0 - bf2f(h0));
        const unsigned short l1 = f2bf(m1 - bf2f(h1));
        const unsigned short l2 = f2bf(m2 - bf2f(h2));
        const unsigned int one = 0x3F80u;
        uint4 r0, r1;
        r0.x = (unsigned int)h0 | ((unsigned int)h1 << 16);  // k0,k1
        r0.y = (unsigned int)h2 | ((unsigned int)h0 << 16);  // k2,k3
        r0.z = (unsigned int)h1 | ((unsigned int)h2 << 16);  // k4,k5
        r0.w = (unsigned int)l0 | ((unsigned int)l1 << 16);  // k6,k7
        r1.x = (unsigned int)l2 | (one << 16);               // k8,k9
        r1.y = one;                                          // k10,k11=0
        r1.z = 0u; r1.w = 0u;
        const uint4 rec = half ? r1 : r0;
        const short8 bfv = *(const short8*)&rec;
        const float  xnv = fmaf(x0, x0, fmaf(x1, x1, x2 * x2));
        if (k == 0) { bf0 = bfv; xn0 = xnv; }
        else if (k == 1) { bf1 = bfv; xn1 = xnv; }
        else if (k == 2) { bf2 = bfv; xn2 = xnv; }
        else { bf3 = bfv; xn3 = xnv; }
    }

    // ---- stage the block's ENTIRE y range once (4 points per thread)
    const float* ypts = yset + (size_t)(b * NPTS + ys * CHUNK) * 3;
    for (int i = t; i < CHUNK; i += 256) {
        const float* yp = ypts + (size_t)i * 3;
        uint4 r0, r1;
        encodeY(yp[0], yp[1], yp[2], &r0, &r1);
        sY[0][i] = r0; sY[1][i] = r1;
    }
    __syncthreads();   // the ONLY barrier

    const floatx16 zc = {0,0,0,0, 0,0,0,0, 0,0,0,0, 0,0,0,0};
    float cmin0 = 3.4e38f, cmin1 = 3.4e38f, cmin2 = 3.4e38f, cmin3 = 3.4e38f;

    const uint4* sYh = &sY[half][0];

#define JBODY()                                                                         \
    do {                                                                                \
        const floatx16 d0 = __builtin_amdgcn_mfma_f32_32x32x16_bf16(af, bf0, zc, 0, 0, 0); \
        const floatx16 d1 = __builtin_amdgcn_mfma_f32_32x32x16_bf16(af, bf1, zc, 0, 0, 0); \
        cmin0 = min16(d0, cmin0);                                                       \
        const floatx16 d2 = __builtin_amdgcn_mfma_f32_32x32x16_bf16(af, bf2, zc, 0, 0, 0); \
        cmin1 = min16(d1, cmin1);                                                       \
        const floatx16 d3 = __builtin_amdgcn_mfma_f32_32x32x16_bf16(af, bf3, zc, 0, 0, 0); \
        cmin2 = min16(d2, cmin2);                                                       \
        cmin3 = min16(d3, cmin3);                                                       \
    } while (0)

    short8 af = *(const short8*)&sYh[l31];
#pragma unroll 8
    for (int j = 0; j < CHUNK / 32 - 1; ++j) {
        const short8 afn = *(const short8*)&sYh[(j + 1) * 32 + l31];  // prefetch
        JBODY();
        af = afn;
    }
    JBODY();   // peeled last iteration (no prefetch)
#undef JBODY

    // merge the two lane-halves (same column, different row halves), add |x|^2;
    // combine across YSPLIT via atomicMin on the uint pattern (values >= 0).
    const float m0 = fminf(cmin0, __shfl_xor(cmin0, 32, 64));
    const float m1 = fminf(cmin1, __shfl_xor(cmin1, 32, 64));
    const float m2 = fminf(cmin2, __shfl_xor(cmin2, 32, 64));
    const float m3 = fminf(cmin3, __shfl_xor(cmin3, 32, 64));
    if (lane < 32) {
        unsigned int* seg = (unsigned int*)wsf;
        atomicMin(&seg[minoff + xw + l31],
                  __float_as_uint(fmaxf(m0 + xn0, 0.0f)));
        atomicMin(&seg[minoff + xw + 32 + l31],
                  __float_as_uint(fmaxf(m1 + xn1, 0.0f)));
        atomicMin(&seg[minoff + xw + 64 + l31],
                  __float_as_uint(fmaxf(m2 + xn2, 0.0f)));
        atomicMin(&seg[minoff + xw + 96 + l31],
                  __float_as_uint(fmaxf(m3 + xn3, 0.0f)));
    }
}

// ---------------------------------------------------------------- reductions
__device__ __forceinline__ float waveReduceSum(float v) {
#pragma unroll
    for (int o = 32; o > 0; o >>= 1) v += __shfl_down(v, o, 64);
    return v;
}

__device__ __forceinline__ float blockReduceSum(float v) {
    __shared__ float wsum[4];
    const int lane = threadIdx.x & 63;
    const int wid  = threadIdx.x >> 6;
    v = waveReduceSum(v);
    if (lane == 0) wsum[wid] = v;
    __syncthreads();
    if (wid == 0) {
        v = (lane < ((int)blockDim.x >> 6)) ? wsum[lane] : 0.0f;
        v = waveReduceSum(v);
    }
    return v;
}

// Blocks 0..63: pf (1024 slots each), 64..127: fp, 128..143: fid, 144: kl.
// (Round-0 structure — its summation order measured absmax 0.0. Unchanged.)
#define NRED_BLOCKS 145
__global__ __launch_bounds__(256) void reduce_finalize_kernel(
        float* __restrict__ wsf,
        const float* __restrict__ mu,
        const float* __restrict__ logvar,
        float* __restrict__ out) {
    float* acc = wsf;
    unsigned int* cnt = (unsigned int*)wsf + 4;
    const int bid = blockIdx.x;
    const int t   = threadIdx.x;

    float v = 0.0f;
    int accIdx;
    if (bid < 144) {
        int base;
        if (bid < 64)       { accIdx = 0; base = DIR_PF  + bid * 1024;         }
        else if (bid < 128) { accIdx = 1; base = DIR_FP  + (bid - 64) * 1024;  }
        else                { accIdx = 2; base = DIR_FID + (bid - 128) * 1024; }
#pragma unroll
        for (int k = 0; k < 4; ++k) {
            const int i = OFF_SEG + base + k * 256 + t;
            v += sqrtf(fmaxf(wsf[i], 1e-12f));
        }
    } else {
        accIdx = 3;
#pragma unroll
        for (int k = 0; k < BATCH * DLAT / 256; ++k) {
            const int i = k * 256 + t;
            const float m = mu[i];
            const float l = logvar[i];
            v += -0.5f * (1.0f + l - m * m - expf(l));
        }
    }

    v = blockReduceSum(v);
    if (t == 0) {
        atomicAdd(&acc[accIdx], v);
        __threadfence();
        const unsigned int done = atomicAdd(cnt, 1u);
        if (done == NRED_BLOCKS - 1) {
            const float s_pf  = atomicAdd(&acc[0], 0.0f);
            const float s_fp  = atomicAdd(&acc[1], 0.0f);
            const float s_fid = atomicAdd(&acc[2], 0.0f);
            const float s_kl  = atomicAdd(&acc[3], 0.0f);
            const float cd  = 0.5f * (s_pf / (float)(BATCH * NPTS) +
                                      s_fp / (float)(BATCH * NPTS));
            const float fid = s_fid / (float)(BATCH * PPTS);
            const float kl  = s_kl / (float)BATCH;
            out[0] = cd + 0.01f * kl + 0.5f * fid;  // CD_W=1, BETA=0.01, FID_W=0.5
            out[1] = cd;
            out[2] = kl;
            out[3] = fid;
        }
    }
}

// ---------------------------------------------------------------- launch
extern "C" void kernel_launch(void* const* d_in, const int* in_sizes, int n_in,
                              void* d_out, int out_size, void* d_ws, size_t ws_size,
                              hipStream_t stream) {
    const float* pred    = (const float*)d_in[0];
    const float* full    = (const float*)d_in[1];
    const float* partial = (const float*)d_in[2];
    const float* mu      = (const float*)d_in[3];
    const float* logvar  = (const float*)d_in[4];
    float* out = (float*)d_out;
    float* wsf = (float*)d_ws;

    // 0. init the single min segment to ~3.4e38 (byte 0x7F -> 0x7F7F7F7F).
    //    Stream-ordered, graph-capturable.
    hipMemsetAsync((char*)d_ws + (size_t)OFF_SEG * sizeof(float), 0x7F,
                   (size_t)SEG * sizeof(float), stream);

    // 1. MFMA min-distance pass (block 0 also zeroes acc+counter)
    minpass_kernel<<<8 * 36 * YSPLIT, 256, 0, stream>>>(pred, full, partial, wsf);

    // 2. all reductions + finalize in one dispatch
    reduce_finalize_kernel<<<NRED_BLOCKS, 256, 0, stream>>>(wsf, mu, logvar, out);
}